// Round 1
// baseline (255.555 us; speedup 1.0000x reference)
//
#include <hip/hip_runtime.h>

#define NCH 16
#define HD  256
#define NL  4
#define NB  16384
#define BM  64
#define OUT_MU 131072
#define OUT_OM 262144

typedef _Float16 half8 __attribute__((ext_vector_type(8)));
typedef _Float16 half4 __attribute__((ext_vector_type(4)));
typedef float    floatx4 __attribute__((ext_vector_type(4)));

#define AS1 __attribute__((address_space(1)))
#define AS3 __attribute__((address_space(3)))

// ---------------------------------------------------------------------------
// Prep: repack hidden-layer weights (fp32 [L][C][256][256], both groups) into
// fp16 chunks laid out [ch(16)][l(4)][kk(8)][kslot(4)][n(256)][e(8)] so that
// (a) a 16 KB chunk is contiguous (linear global_load_lds staging) and
// (b) the MFMA A-operand read (8 consecutive k at row n) is a conflict-free
//     ds_read_b128.
// ---------------------------------------------------------------------------
__global__ void prep_w(const float* __restrict__ Wr_h,
                       const float* __restrict__ Wc_h,
                       _Float16* __restrict__ dst) {
    int v = blockIdx.x * 256 + threadIdx.x;        // 524288 vec8 ids
    int n  = v & 255;
    int s  = (v >> 8) & 3;
    int kk = (v >> 10) & 7;
    int l  = (v >> 13) & 3;
    int ch = v >> 15;
    int k0 = kk * 32 + s * 8;
    const float* src = (ch < 8) ? Wr_h : Wc_h;
    int c = ch & 7;
    const float* p = src + ((size_t)((l * 8 + c) * 256 + n)) * 256 + k0;
    float4 a = *(const float4*)p;
    float4 b = *(const float4*)(p + 4);
    half8 o;
    o[0] = (_Float16)a.x; o[1] = (_Float16)a.y; o[2] = (_Float16)a.z; o[3] = (_Float16)a.w;
    o[4] = (_Float16)b.x; o[5] = (_Float16)b.y; o[6] = (_Float16)b.z; o[7] = (_Float16)b.w;
    *(half8*)(dst + (size_t)v * 8) = o;
}

// ---------------------------------------------------------------------------
// Main fused kernel: block = (channel ch = bid&15, rows m0..m0+63).
// h kept in LDS (fp16, XOR-swizzled slots) across all layers; weights
// double-buffered via global_load_lds. 4 waves, wave wv owns n in
// [wv*64, wv*64+64), all 64 m rows. D[n][m] = sum_k W[n][k]*h[m][k].
// MFMA 16x16x32_f16: A lane: i=l&15, k=(l>>4)*8+e ; B lane: j=l&15, same k;
// D lane: col=l&15 (=m), row=(l>>4)*4+reg (=n_local).
// ---------------------------------------------------------------------------
__global__ __launch_bounds__(256, 2)
void mlp_fused(const float* __restrict__ z,
               const float* __restrict__ Wr_in, const float* __restrict__ br_in,
               const float* __restrict__ br_h,  const float* __restrict__ Wr_out,
               const float* __restrict__ br_out,
               const float* __restrict__ Wc_in, const float* __restrict__ bc_in,
               const float* __restrict__ bc_h,  const float* __restrict__ Wc_out,
               const float* __restrict__ bc_out,
               const _Float16* __restrict__ wst,
               float* __restrict__ out) {
    __shared__ __align__(16) char smem[65536];      // [0,32768)=h, [32768,65536)=2 w-bufs
    const int tid  = threadIdx.x;
    const int lane = tid & 63;
    const int wv   = tid >> 6;
    const int bid  = blockIdx.x;
    const int ch   = bid & 15;                      // channel -> XCD (bid%8) locality
    const int m0   = (bid >> 4) * BM;
    const bool isC = ch >= 8;
    const int c    = ch & 7;
    const int ci0  = ch * 32;                       // first weight chunk of this channel

    // ---- issue stage of chunk 0 early (overlaps input layer) ----
    {
        const char* src = (const char*)wst + (size_t)ci0 * 16384 + wv * 4096 + lane * 16;
        char* dstb = smem + 32768 + wv * 4096;
        #pragma unroll
        for (int i = 0; i < 4; ++i)
            __builtin_amdgcn_global_load_lds((const AS1 void*)(src + i * 1024),
                                             (AS3 void*)(dstb + i * 1024), 16, 0, 0);
    }

    // ---- input layer: h0[m][j] = relu(x * W_in[j] + b_in[j]) ----
    {
        const int m = tid >> 2, q = tid & 3;        // 4 threads per row
        const float* zr = z + (size_t)(m0 + m) * 24;
        float x;
        if (!isC) x = zr[c];
        else { float a = zr[8 + 2 * c], b = zr[9 + 2 * c]; x = a * a + b * b; }
        const float* Wi = (isC ? Wc_in : Wr_in) + c * 256;
        const float* bi = (isC ? bc_in : br_in) + c * 256;
        #pragma unroll
        for (int i = 0; i < 8; ++i) {
            int slot = q * 8 + i, j0 = slot * 8;
            float4 w0 = *(const float4*)(Wi + j0);
            float4 w1 = *(const float4*)(Wi + j0 + 4);
            float4 b0 = *(const float4*)(bi + j0);
            float4 b1 = *(const float4*)(bi + j0 + 4);
            half8 o;
            o[0] = (_Float16)fmaxf(fmaf(x, w0.x, b0.x), 0.f);
            o[1] = (_Float16)fmaxf(fmaf(x, w0.y, b0.y), 0.f);
            o[2] = (_Float16)fmaxf(fmaf(x, w0.z, b0.z), 0.f);
            o[3] = (_Float16)fmaxf(fmaf(x, w0.w, b0.w), 0.f);
            o[4] = (_Float16)fmaxf(fmaf(x, w1.x, b1.x), 0.f);
            o[5] = (_Float16)fmaxf(fmaf(x, w1.y, b1.y), 0.f);
            o[6] = (_Float16)fmaxf(fmaf(x, w1.z, b1.z), 0.f);
            o[7] = (_Float16)fmaxf(fmaf(x, w1.w, b1.w), 0.f);
            *(half8*)(smem + m * 512 + ((slot ^ (m & 7)) * 16)) = o;
        }
    }
    __syncthreads();   // h0 visible; chunk0 staged (vmcnt drained before barrier)

    const float* bh = (isC ? bc_h : br_h) + c * 256;   // + l*2048 per layer

    for (int l = 0; l < NL; ++l) {
        floatx4 acc[4][4];
        #pragma unroll
        for (int a = 0; a < 4; ++a)
            #pragma unroll
            for (int b = 0; b < 4; ++b) acc[a][b] = 0.f;

        #pragma unroll
        for (int kk = 0; kk < 8; ++kk) {
            const int g = l * 8 + kk;
            // prefetch next chunk into other buffer
            if (g + 1 < 32) {
                const char* src = (const char*)wst + (size_t)(ci0 + g + 1) * 16384
                                + wv * 4096 + lane * 16;
                char* dstb = smem + 32768 + ((kk + 1) & 1) * 16384 + wv * 4096;
                #pragma unroll
                for (int i = 0; i < 4; ++i)
                    __builtin_amdgcn_global_load_lds((const AS1 void*)(src + i * 1024),
                                                     (AS3 void*)(dstb + i * 1024), 16, 0, 0);
            }
            const int ks = lane >> 4, r16 = lane & 15;
            const char* wb = smem + 32768 + (kk & 1) * 16384;
            half8 af[4], bf[4];
            #pragma unroll
            for (int nt = 0; nt < 4; ++nt) {
                int n = wv * 64 + nt * 16 + r16;
                af[nt] = *(const half8*)(wb + (ks * 256 + n) * 16);
            }
            #pragma unroll
            for (int mt = 0; mt < 4; ++mt) {
                int m = mt * 16 + r16;
                int slot = kk * 4 + ks;
                bf[mt] = *(const half8*)(smem + m * 512 + ((slot ^ (m & 7)) * 16));
            }
            #pragma unroll
            for (int nt = 0; nt < 4; ++nt)
                #pragma unroll
                for (int mt = 0; mt < 4; ++mt)
                    acc[nt][mt] = __builtin_amdgcn_mfma_f32_16x16x32_f16(
                        af[nt], bf[mt], acc[nt][mt], 0, 0, 0);
            __syncthreads();   // stages drained + all reads of wb/h done
        }

        // ---- epilogue: bias + relu -> h (fp16, swizzled, packed b64 writes) ----
        {
            const int rq = lane >> 4, colm = lane & 15;
            #pragma unroll
            for (int nt = 0; nt < 4; ++nt) {
                const int nb = wv * 64 + nt * 16 + rq * 4;
                float4 b4 = *(const float4*)(bh + l * 2048 + nb);
                #pragma unroll
                for (int mt = 0; mt < 4; ++mt) {
                    const int m = mt * 16 + colm;
                    floatx4 v = acc[nt][mt];
                    half4 o;
                    o[0] = (_Float16)fmaxf(v[0] + b4.x, 0.f);
                    o[1] = (_Float16)fmaxf(v[1] + b4.y, 0.f);
                    o[2] = (_Float16)fmaxf(v[2] + b4.z, 0.f);
                    o[3] = (_Float16)fmaxf(v[3] + b4.w, 0.f);
                    *(half4*)(smem + m * 512 + (((nb >> 3) ^ (m & 7)) * 16) + (nb & 7) * 2) = o;
                }
            }
        }
        __syncthreads();   // new h visible before next layer reads
    }

    // ---- output layer: out = W_out . h + b_out (1 or 2 dots per row) ----
    {
        const int q = tid & 3, m = tid >> 2;
        const float* Wo = isC ? (Wc_out + c * 2 * 256) : (Wr_out + c * 256);
        float s0 = 0.f, s1 = 0.f;
        #pragma unroll
        for (int i = 0; i < 8; ++i) {
            int slot = q * 8 + i;
            half8 hv = *(const half8*)(smem + m * 512 + ((slot ^ (m & 7)) * 16));
            int j0 = slot * 8;
            #pragma unroll
            for (int e = 0; e < 8; ++e) {
                float hf = (float)hv[e];
                s0 = fmaf(hf, Wo[j0 + e], s0);
                if (isC) s1 = fmaf(hf, Wo[256 + j0 + e], s1);
            }
        }
        s0 += __shfl_xor(s0, 1); s0 += __shfl_xor(s0, 2);
        if (isC) { s1 += __shfl_xor(s1, 1); s1 += __shfl_xor(s1, 2); }
        if (q == 0) {
            const int row = m0 + m;
            if (!isC) {
                out[row * 8 + c] = s0 + br_out[c];
            } else {
                out[OUT_MU + row * 8 + c] = s0 + bc_out[c * 2];
                out[OUT_OM + row * 8 + c] = s1 + bc_out[c * 2 + 1];
            }
        }
    }
}

extern "C" void kernel_launch(void* const* d_in, const int* in_sizes, int n_in,
                              void* d_out, int out_size, void* d_ws, size_t ws_size,
                              hipStream_t stream) {
    const float* z      = (const float*)d_in[0];
    const float* Wr_in  = (const float*)d_in[1];
    const float* br_in  = (const float*)d_in[2];
    const float* Wr_h   = (const float*)d_in[3];
    const float* br_h   = (const float*)d_in[4];
    const float* Wr_out = (const float*)d_in[5];
    const float* br_out = (const float*)d_in[6];
    const float* Wc_in  = (const float*)d_in[7];
    const float* bc_in  = (const float*)d_in[8];
    const float* Wc_h   = (const float*)d_in[9];
    const float* bc_h   = (const float*)d_in[10];
    const float* Wc_out = (const float*)d_in[11];
    const float* bc_out = (const float*)d_in[12];
    _Float16* wst = (_Float16*)d_ws;                 // 8 MB repacked fp16 weights
    float* out = (float*)d_out;

    prep_w<<<2048, 256, 0, stream>>>(Wr_h, Wc_h, wst);
    mlp_fused<<<4096, 256, 0, stream>>>(z, Wr_in, br_in, br_h, Wr_out, br_out,
                                        Wc_in, bc_in, bc_h, Wc_out, bc_out, wst, out);
}

// Round 2
// 222.798 us; speedup vs baseline: 1.1470x; 1.1470x over previous
//
#include <hip/hip_runtime.h>

#define OUT_MU 131072
#define OUT_OM 262144
#define BIAS_OFF 4194304      // half-index of bias pack inside d_ws

typedef _Float16 half8 __attribute__((ext_vector_type(8)));
typedef _Float16 half4 __attribute__((ext_vector_type(4)));
typedef float    floatx4 __attribute__((ext_vector_type(4)));

#define AS1 __attribute__((address_space(1)))
#define AS3 __attribute__((address_space(3)))

template<int N> __device__ __forceinline__ void wait_vmcnt() {
    asm volatile("s_waitcnt vmcnt(%0)" :: "i"(N) : "memory");
}
__device__ __forceinline__ void wait_lgkm0() {
    asm volatile("s_waitcnt lgkmcnt(0)" ::: "memory");
}
__device__ __forceinline__ void barrier_raw() {
    asm volatile("s_barrier" ::: "memory");
}

// ---------------------------------------------------------------------------
// Repack hidden weights fp32 -> fp16 as [ch(16)][g(32)][wv(4)][ks(4)][n_l(64)][e(8)]
// so each wave's 4 KB read-slice of every 16 KB chunk is contiguous and can be
// staged wave-privately with global_load_lds (lane*16 linear dst).
// g = l*8+kk ; n = wv*64+n_l ; k = (g&7)*32 + ks*8 + e
// ---------------------------------------------------------------------------
__global__ void prep_w(const float* __restrict__ Wr_h,
                       const float* __restrict__ Wc_h,
                       _Float16* __restrict__ dst) {
    int v = blockIdx.x * 256 + threadIdx.x;        // 524288 half8 slots
    int n_l = v & 63;
    int ks  = (v >> 6) & 3;
    int wv  = (v >> 8) & 3;
    int g   = (v >> 10) & 31;
    int ch  = v >> 15;
    int l = g >> 3, kk = g & 7;
    int n = wv * 64 + n_l;
    int k0 = kk * 32 + ks * 8;
    const float* src = (ch < 8) ? Wr_h : Wc_h;
    int c = ch & 7;
    const float* p = src + ((size_t)((l * 8 + c) * 256 + n)) * 256 + k0;
    float4 a = *(const float4*)p;
    float4 b = *(const float4*)(p + 4);
    half8 o;
    o[0] = (_Float16)a.x; o[1] = (_Float16)a.y; o[2] = (_Float16)a.z; o[3] = (_Float16)a.w;
    o[4] = (_Float16)b.x; o[5] = (_Float16)b.y; o[6] = (_Float16)b.z; o[7] = (_Float16)b.w;
    *(half8*)(dst + (size_t)v * 8) = o;
}

// Bias pack: per (ch, wv, rq) a 64-half block laid out [l(4)][nt(4)][e(4)]
// grouped so bq[j] (half8) = (l = j>>1, nt = (j&1)*2 + {0,1}).
__global__ void prep_b(const float* __restrict__ br_h,
                       const float* __restrict__ bc_h,
                       _Float16* __restrict__ dst) {
    int t = blockIdx.x * 256 + threadIdx.x;        // 16384
    int idx = t & 63, blk = t >> 6;
    int rq = blk & 3, wv = (blk >> 2) & 3, ch = blk >> 4;
    int j = idx >> 3, rem = idx & 7;
    int l = j >> 1, nthi = j & 1;
    int ntlo = rem >> 2, e = rem & 3;
    int nt = nthi * 2 + ntlo;
    int n = wv * 64 + nt * 16 + rq * 4 + e;
    const float* src = (ch < 8) ? br_h : bc_h;
    dst[BIAS_OFF + t] = (_Float16)src[(l * 8 + (ch & 7)) * 256 + n];
}

// ---------------------------------------------------------------------------
// Fused MLP. Block = (ch = bid&15, 64 rows). h lives in LDS (fp16 swizzled)
// across all layers. Weights: 3 rotating wave-private buffers, depth-2
// prefetch, counted vmcnt(8), NO per-step barriers; 2 raw barriers per layer.
// ---------------------------------------------------------------------------
__global__ __launch_bounds__(256, 2)
void mlp_fused(const float* __restrict__ z,
               const float* __restrict__ Wr_in, const float* __restrict__ br_in,
               const float* __restrict__ Wc_in, const float* __restrict__ bc_in,
               const float* __restrict__ Wr_out, const float* __restrict__ br_out,
               const float* __restrict__ Wc_out, const float* __restrict__ bc_out,
               const _Float16* __restrict__ wst,
               float* __restrict__ out) {
    __shared__ __align__(16) char smem[81920];     // [0,32K)=h, [32K,80K)=3 w-bufs
    const int tid  = threadIdx.x;
    const int lane = tid & 63;
    const int wv   = tid >> 6;
    const int bid  = blockIdx.x;
    const int ch   = bid & 15;
    const int m0   = (bid >> 4) * 64;
    const bool isC = ch >= 8;
    const int c    = ch & 7;
    const int ks   = lane >> 4;                    // also rq
    const int r16  = lane & 15;
    const char* wchan = (const char*)wst + (size_t)ch * (32 * 16384);
    const int lane16 = lane << 4;

#define STAGE(G, BUF) do {                                                        \
        const char* _s = wchan + ((size_t)(G) << 14) + (wv << 12) + lane16;       \
        char* _d = smem + 32768 + ((BUF) << 14) + (wv << 12);                     \
        __builtin_amdgcn_global_load_lds((const AS1 void*)_s,          (AS3 void*)_d,          16, 0, 0); \
        __builtin_amdgcn_global_load_lds((const AS1 void*)(_s + 1024), (AS3 void*)(_d + 1024), 16, 0, 0); \
        __builtin_amdgcn_global_load_lds((const AS1 void*)(_s + 2048), (AS3 void*)(_d + 2048), 16, 0, 0); \
        __builtin_amdgcn_global_load_lds((const AS1 void*)(_s + 3072), (AS3 void*)(_d + 3072), 16, 0, 0); \
    } while (0)

    // deepest-first: weight pipeline, then bias pack, then input layer
    STAGE(0, 0);
    STAGE(1, 1);

    half8 bq[8];
    {
        const half8* bp = (const half8*)(wst + BIAS_OFF) + (((ch * 4 + wv) * 4 + ks) * 8);
        #pragma unroll
        for (int j = 0; j < 8; ++j) bq[j] = bp[j];
    }

    // ---- input layer: h0[m][j] = relu(x * W_in[j] + b_in[j]) ----
    {
        const int m = tid >> 2, q = tid & 3;
        const float* zr = z + (size_t)(m0 + m) * 24;
        float x;
        if (!isC) x = zr[c];
        else { float a = zr[8 + 2 * c], b = zr[9 + 2 * c]; x = a * a + b * b; }
        const float* Wi = (isC ? Wc_in : Wr_in) + c * 256;
        const float* bi = (isC ? bc_in : br_in) + c * 256;
        #pragma unroll
        for (int i = 0; i < 8; ++i) {
            int slot = q * 8 + i, j0 = slot * 8;
            float4 w0 = *(const float4*)(Wi + j0);
            float4 w1 = *(const float4*)(Wi + j0 + 4);
            float4 b0 = *(const float4*)(bi + j0);
            float4 b1 = *(const float4*)(bi + j0 + 4);
            half8 o;
            o[0] = (_Float16)fmaxf(fmaf(x, w0.x, b0.x), 0.f);
            o[1] = (_Float16)fmaxf(fmaf(x, w0.y, b0.y), 0.f);
            o[2] = (_Float16)fmaxf(fmaf(x, w0.z, b0.z), 0.f);
            o[3] = (_Float16)fmaxf(fmaf(x, w0.w, b0.w), 0.f);
            o[4] = (_Float16)fmaxf(fmaf(x, w1.x, b1.x), 0.f);
            o[5] = (_Float16)fmaxf(fmaf(x, w1.y, b1.y), 0.f);
            o[6] = (_Float16)fmaxf(fmaf(x, w1.z, b1.z), 0.f);
            o[7] = (_Float16)fmaxf(fmaf(x, w1.w, b1.w), 0.f);
            *(half8*)(smem + m * 512 + ((slot ^ (m & 7)) * 16)) = o;
        }
    }
    wait_lgkm0();
    barrier_raw();                                  // h0 visible

    #pragma unroll
    for (int l = 0; l < 4; ++l) {
        floatx4 acc[4][4];
        #pragma unroll
        for (int a = 0; a < 4; ++a)
            #pragma unroll
            for (int b = 0; b < 4; ++b) acc[a][b] = 0.f;

        #pragma unroll
        for (int kk = 0; kk < 8; ++kk) {
            const int g = l * 8 + kk;               // compile-time (full unroll)
            if (g + 2 < 32) STAGE(g + 2, (g + 2) % 3);
            if (g + 2 < 32)      wait_vmcnt<8>();   // chunk g's 4 loads done
            else if (g + 1 < 32) wait_vmcnt<4>();
            else                 wait_vmcnt<0>();

            const char* wb = smem + 32768 + (g % 3) * 16384 + (wv << 12);
            half8 af[4], bf[4];
            #pragma unroll
            for (int nt = 0; nt < 4; ++nt)
                af[nt] = *(const half8*)(wb + (ks << 10) + ((nt * 16 + r16) << 4));
            #pragma unroll
            for (int mt = 0; mt < 4; ++mt) {
                int m = mt * 16 + r16;
                int slot = kk * 4 + ks;
                bf[mt] = *(const half8*)(smem + m * 512 + ((slot ^ (m & 7)) << 4));
            }
            __builtin_amdgcn_s_setprio(1);
            #pragma unroll
            for (int nt = 0; nt < 4; ++nt)
                #pragma unroll
                for (int mt = 0; mt < 4; ++mt)
                    acc[nt][mt] = __builtin_amdgcn_mfma_f32_16x16x32_f16(
                        af[nt], bf[mt], acc[nt][mt], 0, 0, 0);
            __builtin_amdgcn_s_setprio(0);
        }

        // ---- layer epilogue: bias + relu -> h ----
        wait_lgkm0();
        barrier_raw();                              // (A) all h reads of layer l done
        #pragma unroll
        for (int nt = 0; nt < 4; ++nt) {
            const int nb = wv * 64 + nt * 16 + ks * 4;
            half8 bv = bq[l * 2 + (nt >> 1)];
            float b0 = (float)bv[(nt & 1) * 4 + 0];
            float b1 = (float)bv[(nt & 1) * 4 + 1];
            float b2 = (float)bv[(nt & 1) * 4 + 2];
            float b3 = (float)bv[(nt & 1) * 4 + 3];
            #pragma unroll
            for (int mt = 0; mt < 4; ++mt) {
                const int m = mt * 16 + r16;
                floatx4 v = acc[nt][mt];
                half4 o;
                o[0] = (_Float16)fmaxf(v[0] + b0, 0.f);
                o[1] = (_Float16)fmaxf(v[1] + b1, 0.f);
                o[2] = (_Float16)fmaxf(v[2] + b2, 0.f);
                o[3] = (_Float16)fmaxf(v[3] + b3, 0.f);
                *(half4*)(smem + m * 512 + (((nb >> 3) ^ (m & 7)) * 16) + (nb & 7) * 2) = o;
            }
        }
        wait_lgkm0();
        barrier_raw();                              // (B) new h visible
    }

    // ---- output layer ----
    {
        const int q = tid & 3, m = tid >> 2;
        const float* Wo = isC ? (Wc_out + c * 2 * 256) : (Wr_out + c * 256);
        float s0 = 0.f, s1 = 0.f;
        #pragma unroll
        for (int i = 0; i < 8; ++i) {
            int slot = q * 8 + i;
            half8 hv = *(const half8*)(smem + m * 512 + ((slot ^ (m & 7)) * 16));
            int j0 = slot * 8;
            #pragma unroll
            for (int e = 0; e < 8; ++e) {
                float hf = (float)hv[e];
                s0 = fmaf(hf, Wo[j0 + e], s0);
                if (isC) s1 = fmaf(hf, Wo[256 + j0 + e], s1);
            }
        }
        s0 += __shfl_xor(s0, 1); s0 += __shfl_xor(s0, 2);
        if (isC) { s1 += __shfl_xor(s1, 1); s1 += __shfl_xor(s1, 2); }
        if (q == 0) {
            const int row = m0 + m;
            if (!isC) {
                out[row * 8 + c] = s0 + br_out[c];
            } else {
                out[OUT_MU + row * 8 + c] = s0 + bc_out[c * 2];
                out[OUT_OM + row * 8 + c] = s1 + bc_out[c * 2 + 1];
            }
        }
    }
#undef STAGE
}

extern "C" void kernel_launch(void* const* d_in, const int* in_sizes, int n_in,
                              void* d_out, int out_size, void* d_ws, size_t ws_size,
                              hipStream_t stream) {
    const float* z      = (const float*)d_in[0];
    const float* Wr_in  = (const float*)d_in[1];
    const float* br_in  = (const float*)d_in[2];
    const float* Wr_h   = (const float*)d_in[3];
    const float* br_h   = (const float*)d_in[4];
    const float* Wr_out = (const float*)d_in[5];
    const float* br_out = (const float*)d_in[6];
    const float* Wc_in  = (const float*)d_in[7];
    const float* bc_in  = (const float*)d_in[8];
    const float* Wc_h   = (const float*)d_in[9];
    const float* bc_h   = (const float*)d_in[10];
    const float* Wc_out = (const float*)d_in[11];
    const float* bc_out = (const float*)d_in[12];
    _Float16* wst = (_Float16*)d_ws;               // 8 MB weights + 32 KB bias pack
    float* out = (float*)d_out;

    prep_w<<<2048, 256, 0, stream>>>(Wr_h, Wc_h, wst);
    prep_b<<<64, 256, 0, stream>>>(br_h, bc_h, wst);
    mlp_fused<<<4096, 256, 0, stream>>>(z, Wr_in, br_in, Wc_in, bc_in,
                                        Wr_out, br_out, Wc_out, bc_out, wst, out);
}

// Round 4
// 143.247 us; speedup vs baseline: 1.7840x; 1.5553x over previous
//
#include <hip/hip_runtime.h>

#define OUT_MU 131072
#define OUT_OM 262144
#define BIAS_OFF 4194304              // half-index of bias pack inside d_ws
#define WOUT_OFF 4210688              // half-index of packed W_out

typedef _Float16 half8 __attribute__((ext_vector_type(8)));
typedef _Float16 half4 __attribute__((ext_vector_type(4)));
typedef float    floatx4 __attribute__((ext_vector_type(4)));

__device__ __forceinline__ void wait_lgkm0() {
    asm volatile("s_waitcnt lgkmcnt(0)" ::: "memory");
}
__device__ __forceinline__ void barrier_raw() {
    asm volatile("s_barrier" ::: "memory");
}

// ---------------------------------------------------------------------------
// Repack hidden weights fp32 -> fp16 as
//   [ch(16)][g(32)][wv(4)][nt(4)][ks(4)][r16(16)][e(8)]   (half8 units)
// so lane l of wave wv loads its exact MFMA A-fragment for (g, nt) with one
// global_load_dwordx4. Strides (half8): ch=32768, g=1024, wv=256, nt=64,
// lane = ks*16+r16.
// A-frag (16x16x32_f16): lane l holds row n = nt*16 + (l&15),
//                        k = (g&7)*32 + (l>>4)*8 + e.
// ---------------------------------------------------------------------------
__global__ void prep_w(const float* __restrict__ Wr_h,
                       const float* __restrict__ Wc_h,
                       _Float16* __restrict__ dst) {
    int v = blockIdx.x * 256 + threadIdx.x;        // 524288 half8 slots
    int r16 = v & 15;
    int ks  = (v >> 4) & 3;
    int nt  = (v >> 6) & 3;
    int wv  = (v >> 8) & 3;
    int g   = (v >> 10) & 31;
    int ch  = v >> 15;
    int l = g >> 3, kk = g & 7;
    int n  = wv * 64 + nt * 16 + r16;
    int k0 = kk * 32 + ks * 8;
    const float* src = (ch < 8) ? Wr_h : Wc_h;
    int c = ch & 7;
    const float* p = src + ((size_t)((l * 8 + c) * 256 + n)) * 256 + k0;
    float4 a = *(const float4*)p;
    float4 b = *(const float4*)(p + 4);
    half8 o;
    o[0] = (_Float16)a.x; o[1] = (_Float16)a.y; o[2] = (_Float16)a.z; o[3] = (_Float16)a.w;
    o[4] = (_Float16)b.x; o[5] = (_Float16)b.y; o[6] = (_Float16)b.z; o[7] = (_Float16)b.w;
    *(half8*)(dst + (size_t)v * 8) = o;
}

// Bias pack: per (ch, wv, rq): 64 halves [l(4)][nthi(2)] half8s of [ntlo(2)][e(4)].
__global__ void prep_b(const float* __restrict__ br_h,
                       const float* __restrict__ bc_h,
                       _Float16* __restrict__ dst) {
    int t = blockIdx.x * 256 + threadIdx.x;        // 16384
    int idx = t & 63, blk = t >> 6;
    int rq = blk & 3, wv = (blk >> 2) & 3, ch = blk >> 4;
    int j = idx >> 3, rem = idx & 7;
    int l = j >> 1, nthi = j & 1;
    int ntlo = rem >> 2, e = rem & 3;
    int nt = nthi * 2 + ntlo;
    int n = wv * 64 + nt * 16 + rq * 4 + e;
    const float* src = (ch < 8) ? br_h : bc_h;
    dst[BIAS_OFF + t] = (_Float16)src[(l * 8 + (ch & 7)) * 256 + n];
}

// W_out pack: [ch(16)][d(2)][j(256)] fp16 (real channels use d=0 only).
__global__ void prep_wo(const float* __restrict__ Wr_out,
                        const float* __restrict__ Wc_out,
                        _Float16* __restrict__ dst) {
    int t = blockIdx.x * 256 + threadIdx.x;        // 8192
    int j = t & 255, d = (t >> 8) & 1, ch = t >> 9;
    int c = ch & 7;
    float v;
    if (ch < 8) v = d ? 0.f : Wr_out[c * 256 + j];
    else        v = Wc_out[(c * 2 + d) * 256 + j];
    dst[WOUT_OFF + t] = (_Float16)v;
}

// ---------------------------------------------------------------------------
// Fused MLP. Block = (ch = bid&15, 128 rows). h (128x256 fp16, swizzled) lives
// in LDS across all layers; weights go global->VGPR (wave-exact fragments,
// register double-buffer, depth-1). K-loop has NO barriers; 2 per layer edge.
// Wave wv owns n in [wv*64, wv*64+64), all 128 m rows: acc[4][8].
// ---------------------------------------------------------------------------
__global__ __launch_bounds__(256, 2)
void mlp_fused(const float* __restrict__ z,
               const float* __restrict__ Wr_in, const float* __restrict__ br_in,
               const float* __restrict__ Wc_in, const float* __restrict__ bc_in,
               const float* __restrict__ br_out, const float* __restrict__ bc_out,
               const _Float16* __restrict__ wst,
               float* __restrict__ out) {
    __shared__ __align__(16) char smem[65536];     // h: 128 rows x 512 B
    const int tid  = threadIdx.x;
    const int lane = tid & 63;
    const int wv   = tid >> 6;
    const int bid  = blockIdx.x;
    const int ch   = bid & 15;                     // all same-ch blocks on one XCD
    const int m0   = (bid >> 4) * 128;
    const bool isC = ch >= 8;
    const int c    = ch & 7;
    const int ks   = lane >> 4;
    const int r16  = lane & 15;

    // weight fragments: wlane[g*1024 + nt*64] is this lane's half8 for (g, nt)
    const half8* wlane = (const half8*)wst + (size_t)ch * 32768 + wv * 256 + lane;
    const half8* bp = (const half8*)(wst + BIAS_OFF) + (((ch * 4 + wv) * 4 + ks) * 8);

    half8 wa[4], wb[4];
    #pragma unroll
    for (int nt = 0; nt < 4; ++nt) wa[nt] = wlane[nt * 64];   // g = 0 (issued early)

    // ---- input layer: h0[m][j] = relu(x_m * W_in[j] + b_in[j]) ----
    {
        const int jg = tid & 31;                   // j0 = jg*8
        const int rg = tid >> 5;                   // rows rg*16..rg*16+15
        const float* Wi = (isC ? Wc_in : Wr_in) + c * 256 + jg * 8;
        const float* bi = (isC ? bc_in : br_in) + c * 256 + jg * 8;
        float4 w0 = *(const float4*)Wi;
        float4 w1 = *(const float4*)(Wi + 4);
        float4 v0 = *(const float4*)bi;
        float4 v1 = *(const float4*)(bi + 4);
        #pragma unroll
        for (int i = 0; i < 16; ++i) {
            int m = rg * 16 + i;
            const float* zr = z + (size_t)(m0 + m) * 24;
            float x;
            if (!isC) x = zr[c];
            else { float a = zr[8 + 2 * c], b = zr[9 + 2 * c]; x = a * a + b * b; }
            half8 o;
            o[0] = (_Float16)fmaxf(fmaf(x, w0.x, v0.x), 0.f);
            o[1] = (_Float16)fmaxf(fmaf(x, w0.y, v0.y), 0.f);
            o[2] = (_Float16)fmaxf(fmaf(x, w0.z, v0.z), 0.f);
            o[3] = (_Float16)fmaxf(fmaf(x, w0.w, v0.w), 0.f);
            o[4] = (_Float16)fmaxf(fmaf(x, w1.x, v1.x), 0.f);
            o[5] = (_Float16)fmaxf(fmaf(x, w1.y, v1.y), 0.f);
            o[6] = (_Float16)fmaxf(fmaf(x, w1.z, v1.z), 0.f);
            o[7] = (_Float16)fmaxf(fmaf(x, w1.w, v1.w), 0.f);
            *(half8*)(smem + m * 512 + ((jg ^ (m & 7)) << 4)) = o;
        }
    }
    wait_lgkm0();
    barrier_raw();                                  // h0 visible

#define STEP(KK, WREG) do {                                                       \
        half8 bf[8];                                                              \
        _Pragma("unroll")                                                         \
        for (int mt = 0; mt < 8; ++mt) {                                          \
            int m = mt * 16 + r16;                                                \
            int slot = (KK) * 4 + ks;                                             \
            bf[mt] = *(const half8*)(smem + m * 512 + ((slot ^ (m & 7)) << 4));   \
        }                                                                         \
        __builtin_amdgcn_s_setprio(1);                                            \
        _Pragma("unroll")                                                         \
        for (int nt = 0; nt < 4; ++nt)                                            \
            _Pragma("unroll")                                                     \
            for (int mt = 0; mt < 8; ++mt)                                        \
                acc[nt][mt] = __builtin_amdgcn_mfma_f32_16x16x32_f16(             \
                    WREG[nt], bf[mt], acc[nt][mt], 0, 0, 0);                      \
        __builtin_amdgcn_s_setprio(0);                                            \
    } while (0)

    #pragma unroll 1
    for (int l = 0; l < 4; ++l) {
        half8 bl0 = bp[l * 2], bl1 = bp[l * 2 + 1];
        floatx4 acc[4][8];
        #pragma unroll
        for (int a = 0; a < 4; ++a)
            #pragma unroll
            for (int b = 0; b < 8; ++b) acc[a][b] = 0.f;

        #pragma unroll
        for (int kk = 0; kk < 8; kk += 2) {
            {   // even step: consume wa, prefetch g = l*8+kk+1 into wb
                const half8* p = wlane + (size_t)(l * 8 + kk + 1) * 1024;
                #pragma unroll
                for (int nt = 0; nt < 4; ++nt) wb[nt] = p[nt * 64];
                STEP(kk, wa);
            }
            {   // odd step: consume wb, prefetch g = l*8+kk+2 into wa
                int g1 = l * 8 + kk + 2;
                if (g1 < 32) {
                    const half8* p = wlane + (size_t)g1 * 1024;
                    #pragma unroll
                    for (int nt = 0; nt < 4; ++nt) wa[nt] = p[nt * 64];
                }
                STEP(kk + 1, wb);
            }
        }

        // ---- layer epilogue: bias + relu -> h (in place) ----
        wait_lgkm0();
        barrier_raw();                              // all reads of layer l done
        #pragma unroll
        for (int nt = 0; nt < 4; ++nt) {
            const int nb = wv * 64 + nt * 16 + ks * 4;
            half8 bv = (nt < 2) ? bl0 : bl1;
            float b0 = (float)bv[(nt & 1) * 4 + 0];
            float b1 = (float)bv[(nt & 1) * 4 + 1];
            float b2 = (float)bv[(nt & 1) * 4 + 2];
            float b3 = (float)bv[(nt & 1) * 4 + 3];
            #pragma unroll
            for (int mt = 0; mt < 8; ++mt) {
                const int m = mt * 16 + r16;
                floatx4 v = acc[nt][mt];
                half4 o;
                o[0] = (_Float16)fmaxf(v[0] + b0, 0.f);
                o[1] = (_Float16)fmaxf(v[1] + b1, 0.f);
                o[2] = (_Float16)fmaxf(v[2] + b2, 0.f);
                o[3] = (_Float16)fmaxf(v[3] + b3, 0.f);
                *(half4*)(smem + m * 512 + (((nb >> 3) ^ (m & 7)) << 4) + (nb & 7) * 2) = o;
            }
        }
        wait_lgkm0();
        barrier_raw();                              // new h visible
    }
#undef STEP

    // ---- output layer: 2 threads/row, fp16 packed W_out ----
    {
        const int q = tid & 1, m = tid >> 1;       // m in 0..127
        const half8* Wo = (const half8*)(wst + WOUT_OFF) + ch * 64 + q * 16;
        float s0 = 0.f, s1 = 0.f;
        #pragma unroll
        for (int i = 0; i < 16; ++i) {
            int slot = q * 16 + i;
            half8 hv = *(const half8*)(smem + m * 512 + ((slot ^ (m & 7)) << 4));
            half8 w0 = Wo[i];
            #pragma unroll
            for (int e = 0; e < 8; ++e) s0 = fmaf((float)hv[e], (float)w0[e], s0);
            if (isC) {
                half8 w1 = Wo[32 + i];
                #pragma unroll
                for (int e = 0; e < 8; ++e) s1 = fmaf((float)hv[e], (float)w1[e], s1);
            }
        }
        s0 += __shfl_xor(s0, 1);
        if (isC) s1 += __shfl_xor(s1, 1);
        if (q == 0) {
            const int row = m0 + m;
            if (!isC) {
                out[row * 8 + c] = s0 + br_out[c];
            } else {
                out[OUT_MU + row * 8 + c] = s0 + bc_out[c * 2];
                out[OUT_OM + row * 8 + c] = s1 + bc_out[c * 2 + 1];
            }
        }
    }
}

extern "C" void kernel_launch(void* const* d_in, const int* in_sizes, int n_in,
                              void* d_out, int out_size, void* d_ws, size_t ws_size,
                              hipStream_t stream) {
    const float* z      = (const float*)d_in[0];
    const float* Wr_in  = (const float*)d_in[1];
    const float* br_in  = (const float*)d_in[2];
    const float* Wr_h   = (const float*)d_in[3];
    const float* br_h   = (const float*)d_in[4];
    const float* Wr_out = (const float*)d_in[5];
    const float* br_out = (const float*)d_in[6];
    const float* Wc_in  = (const float*)d_in[7];
    const float* bc_in  = (const float*)d_in[8];
    const float* Wc_h   = (const float*)d_in[9];
    const float* bc_h   = (const float*)d_in[10];
    const float* Wc_out = (const float*)d_in[11];
    const float* bc_out = (const float*)d_in[12];
    _Float16* wst = (_Float16*)d_ws;               // 8 MB weights + bias + wout packs
    float* out = (float*)d_out;

    prep_w<<<2048, 256, 0, stream>>>(Wr_h, Wc_h, wst);
    prep_b<<<64, 256, 0, stream>>>(br_h, bc_h, wst);
    prep_wo<<<32, 256, 0, stream>>>(Wr_out, Wc_out, wst);
    mlp_fused<<<2048, 256, 0, stream>>>(z, Wr_in, br_in, Wc_in, bc_in,
                                        br_out, bc_out, wst, out);
}